// Round 3
// baseline (2432.384 us; speedup 1.0000x reference)
//
#include <hip/hip_runtime.h>

#define TT 2048
#define BB 128
#define II 32
#define HH 128

typedef float v2f __attribute__((ext_vector_type(2)));
typedef float v4f __attribute__((ext_vector_type(4)));
typedef unsigned int u32;
typedef __attribute__((address_space(3))) u32 lds_u32;
typedef const __attribute__((address_space(1))) u32 glb_u32;

// packed dual fp32 FMA (VOP3P)
__device__ __forceinline__ v2f pk_fma(v2f a, v2f b, v2f c) {
    v2f d;
    asm("v_pk_fma_f32 %0, %1, %2, %3" : "=v"(d) : "v"(a), "v"(b), "v"(c));
    return d;
}

// p + dpp(p). 0xB1=quad xor1, 0x4E=quad xor2, 0x124=row_ror:4, 0x128=row_ror:8
template <int CTRL>
__device__ __forceinline__ float dpp_add(float p) {
    int t = __builtin_amdgcn_update_dpp(0, __float_as_int(p), CTRL, 0xF, 0xF, true);
    return p + __int_as_float(t);
}

// ONE WAVE per batch element — barrier-free recurrence.
// Lane pair (2k,2k+1) jointly computes rows 4k..4k+3: even lane does h-cols
// 0..63 / X-cols 0..15, odd lane cols 64..127 / 16..31. Half-sums combine via
// one quad-perm DPP xor1. Lane owns h[2*lane], h[2*lane+1] (write = contiguous
// b64). W_hh/W_in fully in registers. X staged one 8-step window ahead via
// global_load_lds (vmcnt-only). V per step reduced via DPP+readlane into an
// LDS buffer, flushed at the end.
__global__ __launch_bounds__(64, 1)
void vrnn_kernel(const float* __restrict__ X, const float* __restrict__ W_in,
                 const float* __restrict__ W_hh, const float* __restrict__ rnn_bias,
                 const float* __restrict__ alpha, const float* __restrict__ value_W,
                 const float* __restrict__ value_bias, float* __restrict__ out)
{
    const int b    = blockIdx.x;
    const int lane = threadIdx.x;     // 0..63
    const int k    = lane >> 1;       // 0..31 -> rows 4k..4k+3
    const int half = lane & 1;        // col half

    __shared__ __align__(16) float hbuf[2][HH];     // 1 KB ping-pong h state
    __shared__ __align__(16) float xw[2][8][II];    // 2 KB X windows
    __shared__ __align__(16) float vres[TT];        // 8 KB V results

    // ---- weights into registers ----
    v2f wh[4][32];   // rows 4k+r, col pairs (this half): 256 VGPR
    v2f wi[4][8];    // W_in rows, col pairs (this half): 64 VGPR
#pragma unroll
    for (int r = 0; r < 4; ++r) {
        const float* wr = W_hh + (size_t)(4 * k + r) * HH + 64 * half;
#pragma unroll
        for (int c = 0; c < 16; ++c) {
            v4f t = *(const v4f*)(wr + 4 * c);
            wh[r][2 * c]     = (v2f){t.x, t.y};
            wh[r][2 * c + 1] = (v2f){t.z, t.w};
        }
        const float* wir = W_in + (size_t)(4 * k + r) * II + 16 * half;
#pragma unroll
        for (int c = 0; c < 4; ++c) {
            v4f t = *(const v4f*)(wir + 4 * c);
            wi[r][2 * c]     = (v2f){t.x, t.y};
            wi[r][2 * c + 1] = (v2f){t.z, t.w};
        }
    }
    v2f bini[4];
    {
        const v4f b4 = *(const v4f*)(rnn_bias + 4 * k);
        const float m = (half == 0) ? 1.0f : 0.0f;   // bias counted once per pair
        bini[0] = (v2f){b4.x * m, 0.f};
        bini[1] = (v2f){b4.y * m, 0.f};
        bini[2] = (v2f){b4.z * m, 0.f};
        bini[3] = (v2f){b4.w * m, 0.f};
    }
    const v2f al2 = *(const v2f*)(alpha   + 2 * lane);
    const v2f vw2 = *(const v2f*)(value_W + 2 * lane);
    const float vb = value_bias[0];

    // ---- init ----
    ((v2f*)&hbuf[0][0])[lane] = (v2f){0.f, 0.f};
    v2f hreg = (v2f){0.f, 0.f};

    lds_u32* ldsX0 = (lds_u32*)(&xw[0][0][0]);
    lds_u32* ldsX1 = (lds_u32*)(&xw[1][0][0]);

    // prologue: stage window 0 (rows 0..7)
    {
        const float* src = X + (size_t)(lane >> 3) * (BB * II) + b * II + (lane & 7) * 4;
        __builtin_amdgcn_global_load_lds((glb_u32*)src, ldsX0, 16, 0, 0);
    }
    asm volatile("s_waitcnt lgkmcnt(0)" ::: "memory");

    for (int tb = 0; tb < TT; tb += 8) {
        const int w = tb >> 3;
        asm volatile("s_waitcnt vmcnt(0)" ::: "memory");   // window w ready
        if (w + 1 < TT / 8) {                              // prefetch w+1 into other buf
            const float* src = X + (size_t)((w + 1) * 8 + (lane >> 3)) * (BB * II)
                                 + b * II + (lane & 7) * 4;
            __builtin_amdgcn_global_load_lds((glb_u32*)src, (w & 1) ? ldsX0 : ldsX1, 16, 0, 0);
        }
        const float* xwin = &xw[w & 1][0][0];
#pragma unroll
        for (int s = 0; s < 8; ++s) {
            const int p = s & 1;
            const float* hb = &hbuf[p][64 * half];
            const float* xb = xwin + s * II + 16 * half;
            v4f hc[16], xc[4];
#pragma unroll
            for (int i = 0; i < 16; ++i) hc[i] = ((const v4f*)hb)[i];
#pragma unroll
            for (int i = 0; i < 4; ++i)  xc[i] = ((const v4f*)xb)[i];

            v2f aA0 = bini[0], aA1 = bini[1], aA2 = bini[2], aA3 = bini[3];
            v2f aB0 = (v2f){0,0}, aB1 = (v2f){0,0}, aB2 = (v2f){0,0}, aB3 = (v2f){0,0};
#pragma unroll
            for (int i = 0; i < 16; ++i) {
                v2f lo = (v2f){hc[i].x, hc[i].y};
                v2f hi = (v2f){hc[i].z, hc[i].w};
                aA0 = pk_fma(wh[0][2*i],   lo, aA0);
                aA1 = pk_fma(wh[1][2*i],   lo, aA1);
                aA2 = pk_fma(wh[2][2*i],   lo, aA2);
                aA3 = pk_fma(wh[3][2*i],   lo, aA3);
                aB0 = pk_fma(wh[0][2*i+1], hi, aB0);
                aB1 = pk_fma(wh[1][2*i+1], hi, aB1);
                aB2 = pk_fma(wh[2][2*i+1], hi, aB2);
                aB3 = pk_fma(wh[3][2*i+1], hi, aB3);
            }
#pragma unroll
            for (int i = 0; i < 4; ++i) {
                v2f lo = (v2f){xc[i].x, xc[i].y};
                v2f hi = (v2f){xc[i].z, xc[i].w};
                aA0 = pk_fma(wi[0][2*i],   lo, aA0);
                aA1 = pk_fma(wi[1][2*i],   lo, aA1);
                aA2 = pk_fma(wi[2][2*i],   lo, aA2);
                aA3 = pk_fma(wi[3][2*i],   lo, aA3);
                aB0 = pk_fma(wi[0][2*i+1], hi, aB0);
                aB1 = pk_fma(wi[1][2*i+1], hi, aB1);
                aB2 = pk_fma(wi[2][2*i+1], hi, aB2);
                aB3 = pk_fma(wi[3][2*i+1], hi, aB3);
            }
            v2f s0 = aA0 + aB0, s1 = aA1 + aB1, s2 = aA2 + aB2, s3 = aA3 + aB3;
            float p0 = s0.x + s0.y, p1 = s1.x + s1.y;
            float p2 = s2.x + s2.y, p3 = s3.x + s3.y;
            p0 = dpp_add<0xB1>(p0);   // add partner-lane half-sum (same rows)
            p1 = dpp_add<0xB1>(p1);
            p2 = dpp_add<0xB1>(p2);
            p3 = dpp_add<0xB1>(p3);
            const float pa = half ? p2 : p0;
            const float pb = half ? p3 : p1;
            // tanh via exp2/rcp
            const float ea = __builtin_amdgcn_exp2f(pa * 2.8853900817779268f);
            const float eb = __builtin_amdgcn_exp2f(pb * 2.8853900817779268f);
            const float ra = __builtin_amdgcn_rcpf(ea + 1.0f);
            const float rb = __builtin_amdgcn_rcpf(eb + 1.0f);
            v2f ht;
            ht.x = fmaf(-2.0f, ra, 1.0f);
            ht.y = fmaf(-2.0f, rb, 1.0f);
            hreg = pk_fma(al2, ht - hreg, hreg);
            // publish h (contiguous 512B, conflict-free)
            ((v2f*)&hbuf[p ^ 1][0])[lane] = hreg;
            // V reduce (off critical path, fills ds_write latency)
            float c = fmaf(vw2.y, hreg.y, vw2.x * hreg.x);
            c = dpp_add<0xB1>(c); c = dpp_add<0x4E>(c);
            c = dpp_add<0x124>(c); c = dpp_add<0x128>(c);
            const float g1 = __int_as_float(__builtin_amdgcn_readlane(__float_as_int(c), 16));
            const float g2 = __int_as_float(__builtin_amdgcn_readlane(__float_as_int(c), 32));
            const float g3 = __int_as_float(__builtin_amdgcn_readlane(__float_as_int(c), 48));
            if (lane == 0) vres[tb + s] = ((c + g1) + (g2 + g3)) + vb;
            // drain LDS (h write visible to whole wave); no barrier needed
            asm volatile("s_waitcnt lgkmcnt(0)" ::: "memory");
        }
    }

    // ---- epilogue ----
    float* outV = out;
    float* outH = out + (size_t)TT * BB;
    *(v2f*)(outH + (size_t)b * HH + 2 * lane) = hreg;   // last_hidden
#pragma unroll 4
    for (int i = 0; i < TT / 64; ++i) {
        outV[(size_t)(i * 64 + lane) * BB + b] = vres[i * 64 + lane];
    }
}

extern "C" void kernel_launch(void* const* d_in, const int* in_sizes, int n_in,
                              void* d_out, int out_size, void* d_ws, size_t ws_size,
                              hipStream_t stream) {
    const float* X      = (const float*)d_in[0];
    const float* W_in   = (const float*)d_in[1];
    const float* W_hh   = (const float*)d_in[2];
    const float* rbias  = (const float*)d_in[3];
    const float* alpha  = (const float*)d_in[4];
    const float* vW     = (const float*)d_in[5];
    const float* vbias  = (const float*)d_in[6];
    float* out = (float*)d_out;

    vrnn_kernel<<<dim3(BB), dim3(64), 0, stream>>>(X, W_in, W_hh, rbias, alpha, vW, vbias, out);
}

// Round 4
// 871.004 us; speedup vs baseline: 2.7926x; 2.7926x over previous
//
#include <hip/hip_runtime.h>

#define TT 2048
#define BB 128
#define II 32
#define HH 128
#define NW (TT / 8)

typedef float v2f __attribute__((ext_vector_type(2)));
typedef float v4f __attribute__((ext_vector_type(4)));
typedef unsigned int u32;
typedef __attribute__((address_space(3))) u32 lds_u32;
typedef const __attribute__((address_space(1))) u32 glb_u32;

// packed dual fp32 FMA (VOP3P)
__device__ __forceinline__ v2f pk_fma(v2f a, v2f b, v2f c) {
    v2f d;
    asm("v_pk_fma_f32 %0, %1, %2, %3" : "=v"(d) : "v"(a), "v"(b), "v"(c));
    return d;
}

template <int CTRL>
__device__ __forceinline__ float dpp_mov(float p) {
    return __int_as_float(__builtin_amdgcn_update_dpp(0, __float_as_int(p), CTRL, 0xF, 0xF, true));
}
template <int CTRL>
__device__ __forceinline__ float dpp_add(float p) {
    return p + dpp_mov<CTRL>(p);
}

// 8 waves x 64 lanes, one block per batch element.
// Wave w, group g=lane>>4, j=lane&15. Group owns rows base..base+3
// (base=16w+4g); lane j covers h-cols 8j..8j+7 and X-cols 2j..2j+1.
// Recurrence split: z_t = xp_t + M1*H_{t-1} + M2*G_{t-1} with
// M1=W*diag(1-alpha), M2=W*diag(alpha), G=tanh outputs. Only M2*G is on the
// step-critical path; M1*H, the H-chunk update, and the V dot/reduce/store
// are slack work overlapped with LDS latency + barrier wait.
// G exchanged via 48B-strided chunks (2-way bank aliasing only). X staged one
// 8-step window ahead via a single global_load_lds per window (wave 0), with
// vmcnt(0) drained only at each window's last step.
__global__ __launch_bounds__(512)
void vrnn_kernel(const float* __restrict__ X, const float* __restrict__ W_in,
                 const float* __restrict__ W_hh, const float* __restrict__ rnn_bias,
                 const float* __restrict__ alpha, const float* __restrict__ value_W,
                 const float* __restrict__ value_bias, float* __restrict__ out)
{
    const int b    = blockIdx.x;
    const int tid  = threadIdx.x;
    const int wave = tid >> 6;
    const int lane = tid & 63;
    const int g    = lane >> 4;
    const int j    = lane & 15;
    const int base = 16 * wave + 4 * g;

    __shared__ __align__(16) float xw[2][8][II];     // 2 KB X windows
    __shared__ __align__(16) float gbuf[2][192];     // 16 chunks x 12 floats (48B stride)

    // ---- stage window 0 early (overlap HBM latency with weight loads) ----
    if (wave == 0) {
        const float* src = X + (size_t)(lane >> 3) * (BB * II) + b * II + (lane & 7) * 4;
        __builtin_amdgcn_global_load_lds((glb_u32*)src, (lds_u32*)(&xw[0][0][0]), 16, 0, 0);
    }

    // ---- per-lane constants ----
    v2f a_c[4], vwc[4];
#pragma unroll
    for (int i = 0; i < 4; ++i) {
        a_c[i] = *(const v2f*)(alpha   + 8 * j + 2 * i);
        vwc[i] = *(const v2f*)(value_W + 8 * j + 2 * i);
    }
    v2f m1[4][4], m2[4][4], wi[4], binit[4];
#pragma unroll
    for (int r = 0; r < 4; ++r) {
        const float* wr = W_hh + (size_t)(base + r) * HH + 8 * j;
#pragma unroll
        for (int i = 0; i < 4; ++i) {
            v2f w2 = *(const v2f*)(wr + 2 * i);
            m2[r][i] = w2 * a_c[i];
            m1[r][i] = w2 - m2[r][i];
        }
        wi[r]    = *(const v2f*)(W_in + (size_t)(base + r) * II + 2 * j);
        binit[r] = (v2f){ (j == 0) ? rnn_bias[base + r] : 0.0f, 0.0f };
    }
    const float vb = value_bias[0];
    const int  hrow  = base + j;                       // valid writer row for j<4
    const int  gwoff = 12 * (hrow >> 3) + (hrow & 7);  // padded write offset

    v2f hc[4], a1[4];
#pragma unroll
    for (int i = 0; i < 4; ++i) hc[i] = (v2f){0.f, 0.f};
#pragma unroll
    for (int r = 0; r < 4; ++r) a1[r] = binit[r];      // M1*H_{-1} = 0

    if (tid < 192) gbuf[1][tid] = 0.0f;                // G_{-1} = 0
    __syncthreads();

    float* outV = out;
    float* outH = out + (size_t)TT * BB;

    for (int w = 0; w < NW; ++w) {
        // prefetch next window (1 KB, one instruction across the wave)
        if (wave == 0 && w + 1 < NW) {
            const float* src = X + (size_t)((w + 1) * 8 + (lane >> 3)) * (BB * II)
                                 + b * II + (lane & 7) * 4;
            __builtin_amdgcn_global_load_lds((glb_u32*)src,
                (lds_u32*)(&xw[(w + 1) & 1][0][0]), 16, 0, 0);
        }
#pragma unroll
        for (int s = 0; s < 8; ++s) {
            const int par = s & 1;                     // tau&1
            // ---- read G_{tau-1} chunk + x pair ----
            const float* gb = &gbuf[par ^ 1][12 * j];
            const v4f g0 = *(const v4f*)(gb);
            const v4f g1 = *(const v4f*)(gb + 4);
            v2f gp[4] = { (v2f){g0.x, g0.y}, (v2f){g0.z, g0.w},
                          (v2f){g1.x, g1.y}, (v2f){g1.z, g1.w} };
            const v2f xc = *(const v2f*)(&xw[w & 1][s][2 * j]);
            // ---- CRITICAL: z partials = a1 + wi*x + M2*G ----
            float p0, p1, p2, p3;
            {
                v2f a;
                a = pk_fma(wi[0], xc, a1[0]);
                a = pk_fma(m2[0][0], gp[0], a); a = pk_fma(m2[0][1], gp[1], a);
                a = pk_fma(m2[0][2], gp[2], a); a = pk_fma(m2[0][3], gp[3], a);
                p0 = a.x + a.y;
                a = pk_fma(wi[1], xc, a1[1]);
                a = pk_fma(m2[1][0], gp[0], a); a = pk_fma(m2[1][1], gp[1], a);
                a = pk_fma(m2[1][2], gp[2], a); a = pk_fma(m2[1][3], gp[3], a);
                p1 = a.x + a.y;
                a = pk_fma(wi[2], xc, a1[2]);
                a = pk_fma(m2[2][0], gp[0], a); a = pk_fma(m2[2][1], gp[1], a);
                a = pk_fma(m2[2][2], gp[2], a); a = pk_fma(m2[2][3], gp[3], a);
                p2 = a.x + a.y;
                a = pk_fma(wi[3], xc, a1[3]);
                a = pk_fma(m2[3][0], gp[0], a); a = pk_fma(m2[3][1], gp[1], a);
                a = pk_fma(m2[3][2], gp[2], a); a = pk_fma(m2[3][3], gp[3], a);
                p3 = a.x + a.y;
            }
            // ---- reduce-scatter over 16 lanes: lane j ends with row j&3 ----
            const bool b0 = (j & 1) != 0;
            const bool b1 = (j & 2) != 0;
            float rA = (b0 ? p1 : p0) + dpp_mov<0xB1>(b0 ? p0 : p1);
            float rB = (b0 ? p3 : p2) + dpp_mov<0xB1>(b0 ? p2 : p3);
            float pre = (b1 ? rB : rA) + dpp_mov<0x4E>(b1 ? rA : rB);
            pre = dpp_add<0x124>(pre);
            pre = dpp_add<0x128>(pre);
            // ---- tanh, publish G_tau ----
            const float e  = __builtin_amdgcn_exp2f(pre * 2.8853900817779268f);
            const float rc = __builtin_amdgcn_rcpf(e + 1.0f);
            const float gt = fmaf(-2.0f, rc, 1.0f);
            if (j < 4) gbuf[par][gwoff] = gt;
            // ---- SLACK: H update, V_{tau-1}, a1 for next step ----
#pragma unroll
            for (int i = 0; i < 4; ++i) hc[i] = pk_fma(a_c[i], gp[i] - hc[i], hc[i]);
            v2f vt = vwc[0] * hc[0];
            vt = pk_fma(vwc[1], hc[1], vt);
            vt = pk_fma(vwc[2], hc[2], vt);
            vt = pk_fma(vwc[3], hc[3], vt);
            float vsum = vt.x + vt.y;
            vsum = dpp_add<0xB1>(vsum); vsum = dpp_add<0x4E>(vsum);
            vsum = dpp_add<0x124>(vsum); vsum = dpp_add<0x128>(vsum);
            if (wave == s && lane == 0 && (w + s) != 0)
                outV[(size_t)(8 * w + s - 1) * BB + b] = vb + vsum;
#pragma unroll
            for (int r = 0; r < 4; ++r) {
                v2f a = binit[r];
                a = pk_fma(m1[r][0], hc[0], a); a = pk_fma(m1[r][1], hc[1], a);
                a = pk_fma(m1[r][2], hc[2], a); a = pk_fma(m1[r][3], hc[3], a);
                a1[r] = a;
            }
            // ---- barrier (lgkm-only drain; window staging drained at s==7) ----
            if (wave == 0 && s == 7)
                asm volatile("s_waitcnt vmcnt(0)" ::: "memory");
            asm volatile("s_waitcnt lgkmcnt(0)" ::: "memory");
            __builtin_amdgcn_s_barrier();
            __builtin_amdgcn_sched_barrier(0);
        }
    }

    // ---- epilogue: H_T, V[T-1], last_hidden ----
    {
        const float* gb = &gbuf[(TT - 1) & 1][12 * j];
        const v4f g0 = *(const v4f*)(gb);
        const v4f g1 = *(const v4f*)(gb + 4);
        v2f gp[4] = { (v2f){g0.x, g0.y}, (v2f){g0.z, g0.w},
                      (v2f){g1.x, g1.y}, (v2f){g1.z, g1.w} };
#pragma unroll
        for (int i = 0; i < 4; ++i) hc[i] = pk_fma(a_c[i], gp[i] - hc[i], hc[i]);
        v2f vt = vwc[0] * hc[0];
        vt = pk_fma(vwc[1], hc[1], vt);
        vt = pk_fma(vwc[2], hc[2], vt);
        vt = pk_fma(vwc[3], hc[3], vt);
        float vsum = vt.x + vt.y;
        vsum = dpp_add<0xB1>(vsum); vsum = dpp_add<0x4E>(vsum);
        vsum = dpp_add<0x124>(vsum); vsum = dpp_add<0x128>(vsum);
        if (wave == 0 && lane == 0)
            outV[(size_t)(TT - 1) * BB + b] = vb + vsum;
        if (wave == 0 && g == 0) {
#pragma unroll
            for (int i = 0; i < 4; ++i)
                *(v2f*)(outH + (size_t)b * HH + 8 * j + 2 * i) = hc[i];
        }
    }
}

extern "C" void kernel_launch(void* const* d_in, const int* in_sizes, int n_in,
                              void* d_out, int out_size, void* d_ws, size_t ws_size,
                              hipStream_t stream) {
    const float* X      = (const float*)d_in[0];
    const float* W_in   = (const float*)d_in[1];
    const float* W_hh   = (const float*)d_in[2];
    const float* rbias  = (const float*)d_in[3];
    const float* alpha  = (const float*)d_in[4];
    const float* vW     = (const float*)d_in[5];
    const float* vbias  = (const float*)d_in[6];
    float* out = (float*)d_out;

    vrnn_kernel<<<dim3(BB), dim3(512), 0, stream>>>(X, W_in, W_hh, rbias, alpha, vW, vbias, out);
}

// Round 6
// 792.834 us; speedup vs baseline: 3.0680x; 1.0986x over previous
//
#include <hip/hip_runtime.h>

#define TT 2048
#define BB 128
#define II 32
#define HH 128
#define NW (TT / 8)

typedef float v2f __attribute__((ext_vector_type(2)));
typedef float v4f __attribute__((ext_vector_type(4)));
typedef unsigned int u32;
typedef __attribute__((address_space(3))) u32 lds_u32;
typedef const __attribute__((address_space(1))) u32 glb_u32;

// packed dual fp32 FMA (VOP3P)
__device__ __forceinline__ v2f pk_fma(v2f a, v2f b, v2f c) {
    v2f d;
    asm("v_pk_fma_f32 %0, %1, %2, %3" : "=v"(d) : "v"(a), "v"(b), "v"(c));
    return d;
}

// DPP ctrl: 0xB1 quad xor1, 0x4E quad xor2,
// 0x104 row_shl:4 (lane i <- i+4), 0x114 row_shr:4 (lane i <- i-4),
// 0x128 row_ror:8 (== xor8 within 16 lanes)
template <int CTRL>
__device__ __forceinline__ float dpp_mov(float p) {
    return __int_as_float(__builtin_amdgcn_update_dpp(0, __float_as_int(p), CTRL, 0xF, 0xF, true));
}
template <int CTRL>
__device__ __forceinline__ float dpp_add(float p) {
    return p + dpp_mov<CTRL>(p);
}
// reduce-scatter pair stage: lane keeps (sel ? y : x), adds partner's
// complementary partial received via DPP<CTRL>
template <int CTRL>
__device__ __forceinline__ float pair_red(float x, float y, bool sel) {
    float keep = sel ? y : x;
    float give = sel ? x : y;
    return keep + dpp_mov<CTRL>(give);
}

// 4 waves x 64 lanes (256 thr), one block per batch element, 1 wave/SIMD.
// Wave w owns rows 32w..32w+31; 16-lane group g owns 8 rows base=32w+8g..+7;
// lane j (0..15) covers h-cols 8j..8j+7 and X-cols 2j..2j+1. Per step:
// read h chunk (2x b128, 12-float padded chunks), 8 rows x 5 pk_fma, VALU-DPP
// reduce-scatter (xor1,xor2,xor4 via shl/shr+sel, xor8 via ror8) -> lane j
// owns row base+(j&7); tanh; leaky blend in-register; write 1 float. V dot
// reuses the loaded h-chunk regs on one rotating wave per step (h_{t-1} ->
// V_{t-1}). X windows staged one ahead via global_load_lds (wave 0), vmcnt
// drained once per 8 steps. Barrier = lgkm-only drain + raw s_barrier.
__global__ __launch_bounds__(256)
void vrnn_kernel(const float* __restrict__ X, const float* __restrict__ W_in,
                 const float* __restrict__ W_hh, const float* __restrict__ rnn_bias,
                 const float* __restrict__ alpha, const float* __restrict__ value_W,
                 const float* __restrict__ value_bias, float* __restrict__ out)
{
    const int b    = blockIdx.x;
    const int tid  = threadIdx.x;
    const int wave = tid >> 6;        // 0..3
    const int lane = tid & 63;
    const int g    = lane >> 4;       // 0..3
    const int j    = lane & 15;       // 0..15
    const int base = 32 * wave + 8 * g;
    const int rown = base + (j & 7);  // this lane's output row

    __shared__ __align__(16) float xw[2][8][II];     // 2 KB X windows
    __shared__ __align__(16) float hbuf[2][192];     // 16 chunks x 12 floats

    // ---- stage window 0 early ----
    if (wave == 0) {
        const float* src = X + (size_t)(lane >> 3) * (BB * II) + b * II + (lane & 7) * 4;
        __builtin_amdgcn_global_load_lds((glb_u32*)src, (lds_u32*)(&xw[0][0][0]), 16, 0, 0);
    }

    // ---- per-lane constants ----
    v2f wh[8][4], wi8[8], binit[8];
#pragma unroll
    for (int r = 0; r < 8; ++r) {
        const float* wr = W_hh + (size_t)(base + r) * HH + 8 * j;
        v4f a0 = *(const v4f*)(wr);
        v4f a1 = *(const v4f*)(wr + 4);
        wh[r][0] = (v2f){a0.x, a0.y}; wh[r][1] = (v2f){a0.z, a0.w};
        wh[r][2] = (v2f){a1.x, a1.y}; wh[r][3] = (v2f){a1.z, a1.w};
        wi8[r]   = *(const v2f*)(W_in + (size_t)(base + r) * II + 2 * j);
        binit[r] = (v2f){ (j == 0) ? rnn_bias[base + r] : 0.0f, 0.0f };
    }
    v2f vwc[4];
#pragma unroll
    for (int i = 0; i < 4; ++i) vwc[i] = *(const v2f*)(value_W + 8 * j + 2 * i);
    const float al_own = alpha[rown];
    const float vb     = value_bias[0];
    const bool  b0 = (j & 1) != 0;
    const bool  b1 = (j & 2) != 0;
    const bool  b2 = (j & 4) != 0;
    const int   woff = 12 * (4 * wave + g) + (j & 7);   // padded write offset
    float hreg = 0.0f;

    if (tid < 192) hbuf[1][tid] = 0.0f;                 // h_{-1} = 0 (t=0 reads buf 1)
    __syncthreads();

    float* outV = out;
    float* outH = out + (size_t)TT * BB;

    for (int w = 0; w < NW; ++w) {
        if (wave == 0 && w + 1 < NW) {
            const float* src = X + (size_t)((w + 1) * 8 + (lane >> 3)) * (BB * II)
                                 + b * II + (lane & 7) * 4;
            __builtin_amdgcn_global_load_lds((glb_u32*)src,
                (lds_u32*)(&xw[(w + 1) & 1][0][0]), 16, 0, 0);
        }
#pragma unroll
        for (int s = 0; s < 8; ++s) {
            const int par = s & 1;                      // t&1 (t = 8w+s)
            // ---- read h_{t-1} chunk + x pair ----
            const float* hb = &hbuf[par ^ 1][12 * j];
            const v4f h0 = *(const v4f*)(hb);
            const v4f h1 = *(const v4f*)(hb + 4);
            v2f hp[4] = { (v2f){h0.x, h0.y}, (v2f){h0.z, h0.w},
                          (v2f){h1.x, h1.y}, (v2f){h1.z, h1.w} };
            const v2f xc = *(const v2f*)(&xw[w & 1][s][2 * j]);
            // ---- 8 row-partials: 5-deep pk_fma chains ----
            float p[8];
#pragma unroll
            for (int r = 0; r < 8; ++r) {
                v2f a = pk_fma(wi8[r], xc, binit[r]);
                a = pk_fma(wh[r][0], hp[0], a);
                a = pk_fma(wh[r][1], hp[1], a);
                a = pk_fma(wh[r][2], hp[2], a);
                a = pk_fma(wh[r][3], hp[3], a);
                p[r] = a.x + a.y;
            }
            // ---- reduce-scatter 8 rows over 16 lanes (all VALU DPP) ----
            float q0 = pair_red<0xB1>(p[0], p[1], b0);
            float q1 = pair_red<0xB1>(p[2], p[3], b0);
            float q2 = pair_red<0xB1>(p[4], p[5], b0);
            float q3 = pair_red<0xB1>(p[6], p[7], b0);
            float r0 = pair_red<0x4E>(q0, q1, b1);
            float r1 = pair_red<0x4E>(q2, q3, b1);
            // xor4 stage: lane j needs partner j^4's complementary partial.
            // b2=0 (j&4==0): partner at j+4 -> row_shl:4. b2=1: j-4 -> row_shr:4.
            const float k3  = b2 ? r1 : r0;
            const float g3  = b2 ? r0 : r1;
            const float vL  = dpp_mov<0x104>(g3);   // lane i <- i+4
            const float vR  = dpp_mov<0x114>(g3);   // lane i <- i-4
            float pre = k3 + (b2 ? vR : vL);
            pre += dpp_mov<0x128>(pre);             // xor8 (duplicate rows j / j+8)
            // ---- tanh + leaky blend (own row, in-register) ----
            const float e  = __builtin_amdgcn_exp2f(pre * 2.8853900817779268f);
            const float rc = __builtin_amdgcn_rcpf(e + 1.0f);
            const float gt = fmaf(-2.0f, rc, 1.0f);
            hreg = fmaf(al_own, gt - hreg, hreg);
            hbuf[par][woff] = hreg;                 // lanes j and j+8 write same value
            // ---- V_{t-1} on one rotating wave (reuses hp regs = h_{t-1}) ----
            if (wave == (s & 3)) {
                if ((w | s) != 0) {
                    v2f vt = vwc[0] * hp[0];
                    vt = pk_fma(vwc[1], hp[1], vt);
                    vt = pk_fma(vwc[2], hp[2], vt);
                    vt = pk_fma(vwc[3], hp[3], vt);
                    float vs = vt.x + vt.y;
                    vs = dpp_add<0xB1>(vs);
                    vs = dpp_add<0x4E>(vs);
                    const float uL = dpp_mov<0x104>(vs);  // lane i <- i+4
                    const float uR = dpp_mov<0x114>(vs);  // lane i <- i-4
                    vs += b2 ? uR : uL;
                    vs = dpp_add<0x128>(vs);
                    if (lane == 0)
                        outV[(size_t)(8 * w + s - 1) * BB + b] = vb + vs;
                }
            }
            // ---- barrier: lgkm-only drain (vmcnt once per window, wave 0) ----
            if (wave == 0 && s == 7)
                asm volatile("s_waitcnt vmcnt(0)" ::: "memory");
            asm volatile("s_waitcnt lgkmcnt(0)" ::: "memory");
            __builtin_amdgcn_s_barrier();
        }
    }

    // ---- epilogue: V[T-1] from final h (buf parity 1), last_hidden ----
    if (wave == 0) {
        const float* hb = &hbuf[1][12 * j];
        const v4f h0 = *(const v4f*)(hb);
        const v4f h1 = *(const v4f*)(hb + 4);
        v2f hp[4] = { (v2f){h0.x, h0.y}, (v2f){h0.z, h0.w},
                      (v2f){h1.x, h1.y}, (v2f){h1.z, h1.w} };
        v2f vt = vwc[0] * hp[0];
        vt = pk_fma(vwc[1], hp[1], vt);
        vt = pk_fma(vwc[2], hp[2], vt);
        vt = pk_fma(vwc[3], hp[3], vt);
        float vs = vt.x + vt.y;
        vs = dpp_add<0xB1>(vs);
        vs = dpp_add<0x4E>(vs);
        const float uL = dpp_mov<0x104>(vs);
        const float uR = dpp_mov<0x114>(vs);
        vs += b2 ? uR : uL;
        vs = dpp_add<0x128>(vs);
        if (lane == 0)
            outV[(size_t)(TT - 1) * BB + b] = vb + vs;
    }
    if (j < 8)
        outH[(size_t)b * HH + base + j] = hreg;
}

extern "C" void kernel_launch(void* const* d_in, const int* in_sizes, int n_in,
                              void* d_out, int out_size, void* d_ws, size_t ws_size,
                              hipStream_t stream) {
    const float* X      = (const float*)d_in[0];
    const float* W_in   = (const float*)d_in[1];
    const float* W_hh   = (const float*)d_in[2];
    const float* rbias  = (const float*)d_in[3];
    const float* alpha  = (const float*)d_in[4];
    const float* vW     = (const float*)d_in[5];
    const float* vbias  = (const float*)d_in[6];
    float* out = (float*)d_out;

    vrnn_kernel<<<dim3(BB), dim3(256), 0, stream>>>(X, W_in, W_hh, rbias, alpha, vW, vbias, out);
}